// Round 1
// baseline (272.604 us; speedup 1.0000x reference)
//
#include <hip/hip_runtime.h>

// FComb: fused pointwise 4-layer MLP over a 96^3 volume.
// feature_map [1,32,96,96,96] f32 (channel-major), z [1,6],
// w1 [32,38], b1 [32], w2 [32,32], b2 [32], w3 [32,32], b3 [32], wl [1,32], bl [1].
// out [1,1,96,96,96] f32.

constexpr int C0   = 32;
constexpr int LD   = 6;
constexpr int NPTS = 96 * 96 * 96;   // 884736
constexpr int NP2  = NPTS / 2;       // 442368 (each thread does 2 points as float2)
constexpr int BLOCK = 256;

__global__ __launch_bounds__(BLOCK, 2)
void fused_mlp_kernel(const float* __restrict__ fm,
                      const float* __restrict__ z,
                      const float* __restrict__ w1, const float* __restrict__ b1,
                      const float* __restrict__ w2, const float* __restrict__ b2,
                      const float* __restrict__ w3, const float* __restrict__ b3,
                      const float* __restrict__ wl, const float* __restrict__ bl,
                      float* __restrict__ out)
{
    const int t = blockIdx.x * BLOCK + threadIdx.x;   // point-pair index, 0..NP2-1
    const float2* __restrict__ fm2 = reinterpret_cast<const float2*>(fm);

    // ---- load 32 input channels for 2 points (coalesced, 8 B/lane) ----
    float2 xv[C0];
    #pragma unroll
    for (int c = 0; c < C0; ++c) xv[c] = fm2[c * NP2 + t];

    float2 hv[C0];

    // ---- layer 1: h = relu(W1[:, :32] @ x + (b1 + W1[:, 32:38] @ z)) ----
    #pragma unroll
    for (int o = 0; o < C0; ++o) {
        float a0 = b1[o];
        #pragma unroll
        for (int j = 0; j < LD; ++j)
            a0 = fmaf(w1[o * (C0 + LD) + C0 + j], z[j], a0);   // uniform z-fold
        float ax = a0, ay = a0;
        #pragma unroll
        for (int c = 0; c < C0; ++c) {
            const float w = w1[o * (C0 + LD) + c];             // uniform -> SGPR
            ax = fmaf(w, xv[c].x, ax);
            ay = fmaf(w, xv[c].y, ay);
        }
        hv[o] = make_float2(fmaxf(ax, 0.f), fmaxf(ay, 0.f));
    }

    // ---- layer 2: x = relu(W2 @ h + b2) ----
    #pragma unroll
    for (int o = 0; o < C0; ++o) {
        float ax = b2[o], ay = b2[o];
        #pragma unroll
        for (int c = 0; c < C0; ++c) {
            const float w = w2[o * C0 + c];
            ax = fmaf(w, hv[c].x, ax);
            ay = fmaf(w, hv[c].y, ay);
        }
        xv[o] = make_float2(fmaxf(ax, 0.f), fmaxf(ay, 0.f));
    }

    // ---- layer 3: h = relu(W3 @ x + b3) ----
    #pragma unroll
    for (int o = 0; o < C0; ++o) {
        float ax = b3[o], ay = b3[o];
        #pragma unroll
        for (int c = 0; c < C0; ++c) {
            const float w = w3[o * C0 + c];
            ax = fmaf(w, xv[c].x, ax);
            ay = fmaf(w, xv[c].y, ay);
        }
        hv[o] = make_float2(fmaxf(ax, 0.f), fmaxf(ay, 0.f));
    }

    // ---- final: out = wl . h + bl ----
    float ox = bl[0], oy = bl[0];
    #pragma unroll
    for (int c = 0; c < C0; ++c) {
        const float w = wl[c];
        ox = fmaf(w, hv[c].x, ox);
        oy = fmaf(w, hv[c].y, oy);
    }
    reinterpret_cast<float2*>(out)[t] = make_float2(ox, oy);
}

extern "C" void kernel_launch(void* const* d_in, const int* in_sizes, int n_in,
                              void* d_out, int out_size, void* d_ws, size_t ws_size,
                              hipStream_t stream)
{
    const float* fm = (const float*)d_in[0];
    const float* z  = (const float*)d_in[1];
    const float* w1 = (const float*)d_in[2];
    const float* b1 = (const float*)d_in[3];
    const float* w2 = (const float*)d_in[4];
    const float* b2 = (const float*)d_in[5];
    const float* w3 = (const float*)d_in[6];
    const float* b3 = (const float*)d_in[7];
    const float* wl = (const float*)d_in[8];
    const float* bl = (const float*)d_in[9];
    float* out = (float*)d_out;

    fused_mlp_kernel<<<NP2 / BLOCK, BLOCK, 0, stream>>>(
        fm, z, w1, b1, w2, b2, w3, b3, wl, bl, out);
}

// Round 2
// 188.342 us; speedup vs baseline: 1.4474x; 1.4474x over previous
//
#include <hip/hip_runtime.h>

// FComb: fused pointwise 4-layer MLP over 96^3 points, bf16 MFMA version.
// Layers: [32ch + z-fold] -> 32 -> 32 -> 32 -> 1, all 1x1x1 convs (channel GEMMs).
// Mapping per 32-point tile: D[out_ch][pt] = W(32xK) * X(Kxpt) via
// v_mfma_f32_32x32x16_bf16 (2 MFMAs for K=32). Activations split hi+lo bf16
// (2 MFMAs each) so quantization error is dominated by bf16(W) only.
// D layout (verified m74/m101): col=lane&31 (point), row=(r&3)+8*(r>>2)+4*(lane>>5).
// Inter-layer re-layout: cvt_pk_bf16 + 4x permlane32_swap per fragment set (T12).

typedef float  f32x16 __attribute__((ext_vector_type(16)));
typedef short  bf16x8 __attribute__((ext_vector_type(8)));

constexpr int NPTS   = 96 * 96 * 96;   // 884736
constexpr int NP2    = NPTS / 2;       // float2 count per channel
constexpr int BLOCK  = 256;            // 4 waves
constexpr int NBLK   = 864;            // 3456 waves
constexpr int GPW    = 4;              // 64-pt groups per wave; 3456*4*64 = NPTS

union FragU { unsigned u[4]; bf16x8 v; };

__device__ inline unsigned cvtpk(float lo, float hi) {
    unsigned d;
    asm("v_cvt_pk_bf16_f32 %0, %1, %2" : "=v"(d) : "v"(lo), "v"(hi));
    return d;
}
__device__ inline float unlo(unsigned d) { return __uint_as_float(d << 16); }
__device__ inline float unhi(unsigned d) { return __uint_as_float(d & 0xffff0000u); }

__device__ inline bf16x8 mk(unsigned d0, unsigned d1, unsigned d2, unsigned d3) {
    FragU f; f.u[0] = d0; f.u[1] = d1; f.u[2] = d2; f.u[3] = d3; return f.v;
}

// v_permlane32_swap_b32: ret[0] = lane<32 ? a[l] : b[l-32]
//                        ret[1] = lane<32 ? a[l+32] : b[l]
__device__ inline void swap32(unsigned a, unsigned b, unsigned& x, unsigned& y) {
    auto r = __builtin_amdgcn_permlane32_swap(a, b, false, false);
    x = r[0]; y = r[1];
}

// A-fragment: lane holds W[row=lane&31][k = koff + 0..7] as 8 bf16.
__device__ inline bf16x8 load_wfrag(const float* __restrict__ W, int stride,
                                    int row, int koff) {
    const float2* W2 = reinterpret_cast<const float2*>(W + row * stride + koff);
    float2 a = W2[0], b = W2[1], c = W2[2], d = W2[3];
    return mk(cvtpk(a.x, a.y), cvtpk(b.x, b.y), cvtpk(c.x, c.y), cvtpk(d.x, d.y));
}

// From 16 f32 activations (this lane's 16 rows of D, bias included), build the
// next layer's B-fragments (hi + lo split), with relu applied.
__device__ inline void build_bfrags(const float* h,           // 16 floats
                                    bf16x8& B0h, bf16x8& B0l,
                                    bf16x8& B1h, bf16x8& B1l) {
    unsigned hp[8], lp[8];
    #pragma unroll
    for (int j = 0; j < 8; ++j) {
        float h0 = fmaxf(h[2 * j], 0.f), h1 = fmaxf(h[2 * j + 1], 0.f);
        unsigned d = cvtpk(h0, h1);
        hp[j] = d;
        lp[j] = cvtpk(h0 - unlo(d), h1 - unhi(d));
    }
    unsigned a0, a1, b0, b1, c0, c1, d0, d1;
    swap32(hp[0], hp[2], a0, a1); swap32(hp[1], hp[3], b0, b1);
    swap32(hp[4], hp[6], c0, c1); swap32(hp[5], hp[7], d0, d1);
    B0h = mk(a0, b0, a1, b1);
    B1h = mk(c0, d0, c1, d1);
    swap32(lp[0], lp[2], a0, a1); swap32(lp[1], lp[3], b0, b1);
    swap32(lp[4], lp[6], c0, c1); swap32(lp[5], lp[7], d0, d1);
    B0l = mk(a0, b0, a1, b1);
    B1l = mk(c0, d0, c1, d1);
}

__global__ __launch_bounds__(BLOCK, 2)
void fused_mlp_mfma(const float* __restrict__ fm, const float* __restrict__ z,
                    const float* __restrict__ w1, const float* __restrict__ b1,
                    const float* __restrict__ w2, const float* __restrict__ b2,
                    const float* __restrict__ w3, const float* __restrict__ b3,
                    const float* __restrict__ wl, const float* __restrict__ bl,
                    float* __restrict__ out)
{
    const int lane = threadIdx.x & 63;
    const int wid  = blockIdx.x * (BLOCK / 64) + (threadIdx.x >> 6);
    const int hl   = lane >> 5;          // wave half
    const int col  = lane & 31;          // point column == W row
    const int koff = 8 * hl;             // k offset within 16-wide half

    // ---- one-time: weight A-frags (bf16) ----
    bf16x8 W1f[2], W2f[2], W3f[2];
    #pragma unroll
    for (int h = 0; h < 2; ++h) {
        W1f[h] = load_wfrag(w1, 38, col, 16 * h + koff);
        W2f[h] = load_wfrag(w2, 32, col, 16 * h + koff);
        W3f[h] = load_wfrag(w3, 32, col, 16 * h + koff);
    }

    // ---- one-time: bias frags in D layout; z folded into b1 ----
    float zv[6];
    #pragma unroll
    for (int j = 0; j < 6; ++j) zv[j] = z[j];
    f32x16 B1f, B2f, B3f;
    float wlr[16];
    #pragma unroll
    for (int r = 0; r < 16; ++r) {
        const int ch = (r & 3) + 8 * (r >> 2) + 4 * hl;
        float t = b1[ch];
        #pragma unroll
        for (int j = 0; j < 6; ++j) t = fmaf(w1[ch * 38 + 32 + j], zv[j], t);
        B1f[r] = t;
        B2f[r] = b2[ch];
        B3f[r] = b3[ch];
        wlr[r] = wl[ch];
    }
    const float blv = bl[0];

    const float2* __restrict__ fm2 = reinterpret_cast<const float2*>(fm);
    float2* __restrict__ out2      = reinterpret_cast<float2*>(out);

    for (int it = 0; it < GPW; ++it) {
        const int g   = wid * GPW + it;      // 64-point group
        const int pt2 = g * 32 + col;        // float2 index within channel

        // ---- load X: 16 channels x 2 points per lane (coalesced 8B) ----
        float2 v[16];
        #pragma unroll
        for (int i = 0; i < 16; ++i) {
            const int ch = ((i < 8) ? i : (8 + i)) + koff;  // k for this lane
            v[i] = fm2[ch * NP2 + pt2];
        }

        // ---- layer 1 (input already in B-frag layout; split hi/lo) ----
        f32x16 accE = B1f, accO = B1f;
        {
            unsigned he[8], le[8], ho[8], lo_[8];
            #pragma unroll
            for (int j = 0; j < 8; ++j) {
                float e0 = v[2 * j].x, e1 = v[2 * j + 1].x;
                unsigned d = cvtpk(e0, e1);
                he[j] = d; le[j] = cvtpk(e0 - unlo(d), e1 - unhi(d));
                float o0 = v[2 * j].y, o1 = v[2 * j + 1].y;
                unsigned q = cvtpk(o0, o1);
                ho[j] = q; lo_[j] = cvtpk(o0 - unlo(q), o1 - unhi(q));
            }
            accE = __builtin_amdgcn_mfma_f32_32x32x16_bf16(W1f[0], mk(he[0], he[1], he[2], he[3]), accE, 0, 0, 0);
            accE = __builtin_amdgcn_mfma_f32_32x32x16_bf16(W1f[0], mk(le[0], le[1], le[2], le[3]), accE, 0, 0, 0);
            accE = __builtin_amdgcn_mfma_f32_32x32x16_bf16(W1f[1], mk(he[4], he[5], he[6], he[7]), accE, 0, 0, 0);
            accE = __builtin_amdgcn_mfma_f32_32x32x16_bf16(W1f[1], mk(le[4], le[5], le[6], le[7]), accE, 0, 0, 0);
            accO = __builtin_amdgcn_mfma_f32_32x32x16_bf16(W1f[0], mk(ho[0], ho[1], ho[2], ho[3]), accO, 0, 0, 0);
            accO = __builtin_amdgcn_mfma_f32_32x32x16_bf16(W1f[0], mk(lo_[0], lo_[1], lo_[2], lo_[3]), accO, 0, 0, 0);
            accO = __builtin_amdgcn_mfma_f32_32x32x16_bf16(W1f[1], mk(ho[4], ho[5], ho[6], ho[7]), accO, 0, 0, 0);
            accO = __builtin_amdgcn_mfma_f32_32x32x16_bf16(W1f[1], mk(lo_[4], lo_[5], lo_[6], lo_[7]), accO, 0, 0, 0);
        }

        // ---- layers 2 and 3 ----
        f32x16 nE, nO;
        {
            float hE[16], hO[16];
            #pragma unroll
            for (int r = 0; r < 16; ++r) { hE[r] = accE[r]; hO[r] = accO[r]; }
            bf16x8 E0h, E0l, E1h, E1l, O0h, O0l, O1h, O1l;
            build_bfrags(hE, E0h, E0l, E1h, E1l);
            build_bfrags(hO, O0h, O0l, O1h, O1l);
            nE = B2f; nO = B2f;
            nE = __builtin_amdgcn_mfma_f32_32x32x16_bf16(W2f[0], E0h, nE, 0, 0, 0);
            nE = __builtin_amdgcn_mfma_f32_32x32x16_bf16(W2f[0], E0l, nE, 0, 0, 0);
            nE = __builtin_amdgcn_mfma_f32_32x32x16_bf16(W2f[1], E1h, nE, 0, 0, 0);
            nE = __builtin_amdgcn_mfma_f32_32x32x16_bf16(W2f[1], E1l, nE, 0, 0, 0);
            nO = __builtin_amdgcn_mfma_f32_32x32x16_bf16(W2f[0], O0h, nO, 0, 0, 0);
            nO = __builtin_amdgcn_mfma_f32_32x32x16_bf16(W2f[0], O0l, nO, 0, 0, 0);
            nO = __builtin_amdgcn_mfma_f32_32x32x16_bf16(W2f[1], O1h, nO, 0, 0, 0);
            nO = __builtin_amdgcn_mfma_f32_32x32x16_bf16(W2f[1], O1l, nO, 0, 0, 0);
        }
        {
            float hE[16], hO[16];
            #pragma unroll
            for (int r = 0; r < 16; ++r) { hE[r] = nE[r]; hO[r] = nO[r]; }
            bf16x8 E0h, E0l, E1h, E1l, O0h, O0l, O1h, O1l;
            build_bfrags(hE, E0h, E0l, E1h, E1l);
            build_bfrags(hO, O0h, O0l, O1h, O1l);
            accE = B3f; accO = B3f;
            accE = __builtin_amdgcn_mfma_f32_32x32x16_bf16(W3f[0], E0h, accE, 0, 0, 0);
            accE = __builtin_amdgcn_mfma_f32_32x32x16_bf16(W3f[0], E0l, accE, 0, 0, 0);
            accE = __builtin_amdgcn_mfma_f32_32x32x16_bf16(W3f[1], E1h, accE, 0, 0, 0);
            accE = __builtin_amdgcn_mfma_f32_32x32x16_bf16(W3f[1], E1l, accE, 0, 0, 0);
            accO = __builtin_amdgcn_mfma_f32_32x32x16_bf16(W3f[0], O0h, accO, 0, 0, 0);
            accO = __builtin_amdgcn_mfma_f32_32x32x16_bf16(W3f[0], O0l, accO, 0, 0, 0);
            accO = __builtin_amdgcn_mfma_f32_32x32x16_bf16(W3f[1], O1h, accO, 0, 0, 0);
            accO = __builtin_amdgcn_mfma_f32_32x32x16_bf16(W3f[1], O1l, accO, 0, 0, 0);
        }

        // ---- final 1x32 dot in f32 (relu'd), cross-half reduce, store ----
        float sE = 0.f, sO = 0.f;
        #pragma unroll
        for (int r = 0; r < 16; ++r) {
            sE = fmaf(wlr[r], fmaxf(accE[r], 0.f), sE);
            sO = fmaf(wlr[r], fmaxf(accO[r], 0.f), sO);
        }
        unsigned px, py;
        swap32(__float_as_uint(sE), __float_as_uint(sE), px, py);
        float totE = __uint_as_float(px) + __uint_as_float(py) + blv;
        swap32(__float_as_uint(sO), __float_as_uint(sO), px, py);
        float totO = __uint_as_float(px) + __uint_as_float(py) + blv;

        if (lane < 32) out2[pt2] = make_float2(totE, totO);
    }
}

extern "C" void kernel_launch(void* const* d_in, const int* in_sizes, int n_in,
                              void* d_out, int out_size, void* d_ws, size_t ws_size,
                              hipStream_t stream)
{
    const float* fm = (const float*)d_in[0];
    const float* z  = (const float*)d_in[1];
    const float* w1 = (const float*)d_in[2];
    const float* b1 = (const float*)d_in[3];
    const float* w2 = (const float*)d_in[4];
    const float* b2 = (const float*)d_in[5];
    const float* w3 = (const float*)d_in[6];
    const float* b3 = (const float*)d_in[7];
    const float* wl = (const float*)d_in[8];
    const float* bl = (const float*)d_in[9];
    float* out = (float*)d_out;

    fused_mlp_mfma<<<NBLK, BLOCK, 0, stream>>>(
        fm, z, w1, b1, w2, b2, w3, b3, wl, bl, out);
}